// Round 11
// baseline (135.353 us; speedup 1.0000x reference)
//
#include <hip/hip_runtime.h>

typedef unsigned int uint_t;
typedef unsigned short ushort_t;

constexpr int MAXDEG = 64;   // slots per node row; deg ~ Poisson(16): P(deg >= 64) ~ 3e-22
// R1: cacheline-padding cursor REGRESSED — same-line atomic contention is NOT the issue.
// R2: batching 4 atomics 114->73us — atomic LATENCY chain was ~40us.
// R3: vmcnt-overlap schedule: NULL — fill cost is memory-side THROUGHPUT.
// R4: XCD-sliced edge regions: NULL — write excess tracks the ATOMIC count (64B/atomic).
// R5: gemm2 -> bf16 MFMA split-W (Whi+Wlo, fp32 acc): WIN 175->167, absmax unchanged.
// R6: pair-gather aggs: ~5us win -> aggs BW-bound (~435MB random 256B gathers) = near floor.
// R7: LDS-binned CSR build at 49 blocks = 1.7% occupancy: 43.8us. Concept right, no parallelism.
// R8: shift=7 (128-node buckets, ~391 blocks): WIN 177->145.6. Build ~8us total.
// R9: gemm1 MFMA: CRASHED (bucketcnt zeroing covered only [0..255] -> OOB bucket writes).
// R10: fixed zeroing: WIN 145.6->126.2, absmax unchanged. Both GEMMs now MFMA split-form.
// R11: fuse agg2 into gemm2 — agg2's bufG output (12.8MB NT store) was re-read by gemm2 from
//     HBM. Fused: 4 waves aggregate 16 nodes each into 17KB LDS (identical numerics: f32
//     accum, x sc, bf16 pack), barrier, MFMA reads A-frags from LDS. -25.6MB, -1 launch.
//     Risk (stated): fused grid = 782 blocks = 12 waves/CU vs 32 for standalone agg.

// ---------------- bf16 helpers (RNE) ----------------
static __device__ __forceinline__ uint_t f2bf_bits(float f) {
  uint_t u = __builtin_bit_cast(uint_t, f);
  return (u + 0x7fffu + ((u >> 16) & 1u)) >> 16;
}
static __device__ __forceinline__ uint_t pack_bf2(float lo, float hi) {
  return f2bf_bits(lo) | (f2bf_bits(hi) << 16);
}
static __device__ __forceinline__ float bf_lo(uint_t u) {
  return __builtin_bit_cast(float, u << 16);
}
static __device__ __forceinline__ float bf_hi(uint_t u) {
  return __builtin_bit_cast(float, u & 0xffff0000u);
}

// ---------------- vector types ----------------
typedef __attribute__((ext_vector_type(2))) uint_t v2u;
typedef __attribute__((ext_vector_type(8))) short  short8_t;  // 8 bf16 (4 VGPRs)
typedef __attribute__((ext_vector_type(4))) float  f32x4_t;   // MFMA acc

static __device__ __forceinline__ void stnt_u2(uint_t* p, uint_t a, uint_t b) {
  v2u t; t.x = a; t.y = b;
  __builtin_nontemporal_store(t, (v2u*)p);
}

static inline size_t align256(size_t x) { return (x + 255) & ~(size_t)255; }

// ---------------- Phase A: bin edges into dst-range buckets (<=512) ----------------
__global__ __launch_bounds__(256) void bucket_scatter_kernel(
    const int* __restrict__ src, const int* __restrict__ dst,
    uint2* __restrict__ buckets, int* __restrict__ bucketcnt,
    int E, int C, int shift, int NB) {
  __shared__ int hist[512];
  __shared__ int base[512];
  const int tid = threadIdx.x;
  const int e0 = blockIdx.x * 2048;

  for (int i = tid; i < NB; i += 256) hist[i] = 0;
  __syncthreads();

  int dd[8], ss[8], slot[8];
#pragma unroll
  for (int i = 0; i < 8; ++i) {
    int e = e0 + tid + i * 256;
    bool ok = (e < E);
    dd[i] = ok ? dst[e] : -1;
    ss[i] = ok ? src[e] : 0;
    slot[i] = ok ? atomicAdd(&hist[dd[i] >> shift], 1) : 0;
  }
  __syncthreads();

  for (int i = tid; i < NB; i += 256) {
    int c = hist[i];
    base[i] = (c > 0) ? atomicAdd(&bucketcnt[i], c) : 0;
  }
  __syncthreads();

#pragma unroll
  for (int i = 0; i < 8; ++i) {
    if (dd[i] < 0) continue;
    int b = dd[i] >> shift;
    int pos = base[b] + slot[i];
    if (pos >= 0 && pos < C)  // capacity + sign guard
      buckets[(size_t)b * C + pos] = make_uint2((uint_t)dd[i], (uint_t)ss[i]);
  }
}

// ---------------- Phase B: bucket -> 64-slot CSR rows + deg, all in LDS ----------------
template<typename IdxT, int WIN>
__global__ __launch_bounds__(256) void bucket_to_rows_kernel(
    const uint2* __restrict__ buckets, const int* __restrict__ bucketcnt,
    IdxT* __restrict__ edge, int* __restrict__ deg, int Nn, int C, int shift) {
  __shared__ __align__(16) IdxT rows[WIN * MAXDEG];
  __shared__ int cnt[WIN];
  const int tid = threadIdx.x;
  const int b = blockIdx.x;
  const int node0 = b << shift;
  const int RANGE = 1 << shift;
  int ec = bucketcnt[b];
  if (ec > C) ec = C;
  if (ec < 0) ec = 0;
  const uint2* bb = buckets + (size_t)b * C;

  for (int w0 = 0; w0 < RANGE; w0 += WIN) {
    for (int i = tid; i < WIN; i += 256) cnt[i] = 0;
    __syncthreads();
    for (int i = tid; i < ec; i += 256) {
      uint2 it = bb[i];
      int local = (int)it.x - node0 - w0;
      if (local >= 0 && local < WIN) {
        int sl = atomicAdd(&cnt[local], 1);
        if (sl < MAXDEG) rows[local * MAXDEG + sl] = (IdxT)it.y;
      }
    }
    __syncthreads();
    const int nbase = node0 + w0;
    constexpr int PER = (MAXDEG * sizeof(IdxT)) / 16;  // uint4 per node row
    const uint4* rv = (const uint4*)rows;
    uint4* ev = (uint4*)(edge + (size_t)nbase * MAXDEG);
    for (int i = tid; i < WIN * PER; i += 256) {
      int node = nbase + i / PER;
      if (node < Nn) ev[i] = rv[i];
    }
    for (int i = tid; i < WIN; i += 256) {
      int node = nbase + i;
      if (node < Nn) deg[node] = cnt[i];  // raw count (agg clamps)
    }
    __syncthreads();
  }
}

// ---------------- pack weights into MFMA B-fragment order, split hi/lo ----------------
// Blocks 0-7:  W1 (128x128)       -> B1hi/B1lo
// Blocks 8-15: [W3|W4] (128x128)  -> B2hi/B2lo
// Block 0 also zeroes bucketcnt[512] (2 entries/thread).
__global__ __launch_bounds__(256) void pack_w_kernel(
    const float* __restrict__ W1, const float* __restrict__ W3,
    const float* __restrict__ W4,
    ushort_t* __restrict__ B1hi, ushort_t* __restrict__ B1lo,
    ushort_t* __restrict__ B2hi, ushort_t* __restrict__ B2lo,
    int* __restrict__ bucketcnt) {
  if (blockIdx.x == 0) {
    bucketcnt[threadIdx.x] = 0;
    bucketcnt[threadIdx.x + 256] = 0;
  }
  const bool w1 = (blockIdx.x < 8);
  int u = (w1 ? blockIdx.x : blockIdx.x - 8) * 256 + threadIdx.x;  // 0..2047
  int l = u & 63, kk = (u >> 6) & 3, t = u >> 8;
  int q = l >> 4, c = l & 15;
  int n = t * 16 + c;
  short8_t vh, vl;
#pragma unroll
  for (int j = 0; j < 8; ++j) {
    int k = kk * 32 + q * 8 + j;
    float w;
    if (w1)          w = W1[(size_t)k * 128 + n];
    else if (n < 64) w = W3[(size_t)k * 64 + n];
    else             w = W4[(size_t)k * 64 + (n - 64)];
    uint_t hb = f2bf_bits(w);
    float wl = w - __builtin_bit_cast(float, hb << 16);
    vh[j] = (short)hb;
    vl[j] = (short)f2bf_bits(wl);
  }
  ushort_t* ph = w1 ? B1hi : B2hi;
  ushort_t* pl = w1 ? B1lo : B2lo;
  *(short8_t*)(ph + (size_t)u * 8) = vh;
  *(short8_t*)(pl + (size_t)u * 8) = vl;
}

// ---------------- GEMM1 (MFMA): outG(bf16) = X @ W1, both operands hi/lo-split ----------------
__global__ __launch_bounds__(256) void gemm1_mfma_kernel(
    const float* __restrict__ X, const ushort_t* __restrict__ Bhi,
    const ushort_t* __restrict__ Blo, ushort_t* __restrict__ outG, int Nrows) {
  const int tid = threadIdx.x;
  const int wid = tid >> 6;
  const int lane = tid & 63;
  const int q = lane >> 4;
  const int c = lane & 15;
  const int rowbase = blockIdx.x * 64 + wid * 16;

  f32x4_t acc[8];
#pragma unroll
  for (int t = 0; t < 8; ++t) acc[t] = (f32x4_t){0.f, 0.f, 0.f, 0.f};

  int arow = rowbase + c;
  int ars = (arow < Nrows) ? arow : (Nrows - 1);
  const float* abase = X + (size_t)ars * 128 + q * 8;

#pragma unroll
  for (int kk = 0; kk < 4; ++kk) {
    float4 xa = *(const float4*)(abase + kk * 32);
    float4 xb = *(const float4*)(abase + kk * 32 + 4);
    float xf[8] = {xa.x, xa.y, xa.z, xa.w, xb.x, xb.y, xb.z, xb.w};
    short8_t ahi, alo;
#pragma unroll
    for (int j = 0; j < 8; ++j) {
      float f = xf[j];
      uint_t hb = f2bf_bits(f);
      ahi[j] = (short)hb;
      float fl = f - __builtin_bit_cast(float, hb << 16);
      alo[j] = (short)f2bf_bits(fl);
    }
#pragma unroll
    for (int t = 0; t < 8; ++t) {
      const size_t fo = ((size_t)(t * 4 + kk) * 64 + lane) * 8;
      short8_t bh = *(const short8_t*)(Bhi + fo);
      short8_t bl = *(const short8_t*)(Blo + fo);
      acc[t] = __builtin_amdgcn_mfma_f32_16x16x32_bf16(ahi, bh, acc[t], 0, 0, 0);
      acc[t] = __builtin_amdgcn_mfma_f32_16x16x32_bf16(ahi, bl, acc[t], 0, 0, 0);
      acc[t] = __builtin_amdgcn_mfma_f32_16x16x32_bf16(alo, bh, acc[t], 0, 0, 0);
    }
  }

#pragma unroll
  for (int t = 0; t < 8; ++t) {
#pragma unroll
    for (int rr = 0; rr < 4; ++rr) {
      int row = rowbase + q * 4 + rr;
      if (row < Nrows)
        outG[(size_t)row * 128 + t * 16 + c] = (ushort_t)f2bf_bits(acc[t][rr]);
    }
  }
}

// ---------------- agg1: pair-gather (SRCDV + relu epilogue), standalone ----------------
template<typename IdxT>
__global__ __launch_bounds__(256) void aggregate1_kernel(
    const uint_t* __restrict__ g, const int* __restrict__ deg,
    const IdxT* __restrict__ edge, const float* __restrict__ b1,
    uint_t* __restrict__ out, int Nn) {
  const int wave = threadIdx.x >> 6;
  const int lane = threadIdx.x & 63;
  const int n = blockIdx.x * 4 + wave;
  if (n >= Nn) return;
  const int dn = deg[n];
  const int cnt = (dn > 63) ? 63 : dn;
  const float sc = rsqrtf((float)(dn + 1));

  int vl = n;
  if (lane >= 1 && lane <= cnt) vl = (int)edge[(size_t)n * MAXDEG + (lane - 1)];
  float wl = 0.f;
  if (lane == 0)        wl = sc;
  else if (lane <= cnt) wl = rsqrtf((float)(deg[vl] + 1));

  const int h = lane >> 5;
  const int c = lane & 31;
  const uint_t* gc = g + c * 2;

  float a0 = 0.f, a1 = 0.f, a2 = 0.f, a3 = 0.f;
  const int entries = cnt + 1;
  const int npairs = (entries + 1) >> 1;

  int p = 0;
  for (; p + 4 <= npairs; p += 4) {
    int ss[4]; float ww[4]; uint2 uu[4];
#pragma unroll
    for (int t = 0; t < 4; ++t) {
      int j = 2 * (p + t) + h;
      ss[t] = __shfl(vl, j);
      ww[t] = __shfl(wl, j);
    }
#pragma unroll
    for (int t = 0; t < 4; ++t)
      uu[t] = *(const uint2*)(gc + (size_t)ss[t] * 64);
#pragma unroll
    for (int t = 0; t < 4; ++t) {
      a0 = fmaf(ww[t], bf_lo(uu[t].x), a0);
      a1 = fmaf(ww[t], bf_hi(uu[t].x), a1);
      a2 = fmaf(ww[t], bf_lo(uu[t].y), a2);
      a3 = fmaf(ww[t], bf_hi(uu[t].y), a3);
    }
  }
  for (; p < npairs; ++p) {
    int j = 2 * p + h;
    int s0 = __shfl(vl, j);
    float w0 = __shfl(wl, j);
    uint2 u = *(const uint2*)(gc + (size_t)s0 * 64);
    a0 = fmaf(w0, bf_lo(u.x), a0);
    a1 = fmaf(w0, bf_hi(u.x), a1);
    a2 = fmaf(w0, bf_lo(u.y), a2);
    a3 = fmaf(w0, bf_hi(u.y), a3);
  }

  a0 += __shfl_xor(a0, 32);
  a1 += __shfl_xor(a1, 32);
  a2 += __shfl_xor(a2, 32);
  a3 += __shfl_xor(a3, 32);

  if (h == 0) {
    float4 b = ((const float4*)b1)[c];
    a0 = fmaxf(fmaf(sc, a0, b.x), 0.f) * sc;
    a1 = fmaxf(fmaf(sc, a1, b.y), 0.f) * sc;
    a2 = fmaxf(fmaf(sc, a2, b.z), 0.f) * sc;
    a3 = fmaxf(fmaf(sc, a3, b.w), 0.f) * sc;
    stnt_u2(out + (size_t)n * 64 + c * 2, pack_bf2(a0, a1), pack_bf2(a2, a3));
  }
}

// ---------------- fused agg2 + GEMM2 ----------------
// Step 1: each wave pair-gather-aggregates 16 nodes (EPI2 numerics: f32 accum, x sc,
// bf16 pack — bit-identical to the old standalone chain) into LDS [64][68] uint.
// Step 2: split-W MFMA with A-frags ds_read from LDS; epilogue = +bias, fp32 NT stores.
template<typename IdxT>
__global__ __launch_bounds__(256) void agg2_gemm2_kernel(
    const uint_t* __restrict__ g, const int* __restrict__ deg,
    const IdxT* __restrict__ edge,
    const ushort_t* __restrict__ Bhi, const ushort_t* __restrict__ Blo,
    const float* __restrict__ b3, const float* __restrict__ b4,
    float* __restrict__ outM, float* __restrict__ outS, int Nn) {
  __shared__ uint_t lds_h[64][68];  // 64 rows x 128 bf16, +4 uint pad (2-way banks = free)
  const int tid = threadIdx.x;
  const int wid = tid >> 6;
  const int lane = tid & 63;
  const int rowbase = blockIdx.x * 64;

  // ---- step 1: aggregate this wave's 16 rows into LDS ----
  {
    const int h = lane >> 5;
    const int c = lane & 31;
    const uint_t* gc = g + c * 2;
    for (int i = 0; i < 16; ++i) {
      const int r = wid * 16 + i;
      const int n = rowbase + r;
      if (n >= Nn) {
        if (h == 0) { lds_h[r][c * 2] = 0; lds_h[r][c * 2 + 1] = 0; }
        continue;
      }
      const int dn = deg[n];
      const int cnt = (dn > 63) ? 63 : dn;
      const float sc = rsqrtf((float)(dn + 1));
      int vl = n;
      if (lane >= 1 && lane <= cnt) vl = (int)edge[(size_t)n * MAXDEG + (lane - 1)];
      const float wl = (lane <= cnt) ? 1.f : 0.f;

      float a0 = 0.f, a1 = 0.f, a2 = 0.f, a3 = 0.f;
      const int npairs = (cnt + 2) >> 1;  // entries = cnt+1
      int p = 0;
      for (; p + 4 <= npairs; p += 4) {
        int ss[4]; float ww[4]; uint2 uu[4];
#pragma unroll
        for (int t = 0; t < 4; ++t) {
          int j = 2 * (p + t) + h;
          ss[t] = __shfl(vl, j);
          ww[t] = __shfl(wl, j);
        }
#pragma unroll
        for (int t = 0; t < 4; ++t)
          uu[t] = *(const uint2*)(gc + (size_t)ss[t] * 64);
#pragma unroll
        for (int t = 0; t < 4; ++t) {
          a0 = fmaf(ww[t], bf_lo(uu[t].x), a0);
          a1 = fmaf(ww[t], bf_hi(uu[t].x), a1);
          a2 = fmaf(ww[t], bf_lo(uu[t].y), a2);
          a3 = fmaf(ww[t], bf_hi(uu[t].y), a3);
        }
      }
      for (; p < npairs; ++p) {
        int j = 2 * p + h;
        int s0 = __shfl(vl, j);
        float w0 = __shfl(wl, j);
        uint2 u = *(const uint2*)(gc + (size_t)s0 * 64);
        a0 = fmaf(w0, bf_lo(u.x), a0);
        a1 = fmaf(w0, bf_hi(u.x), a1);
        a2 = fmaf(w0, bf_lo(u.y), a2);
        a3 = fmaf(w0, bf_hi(u.y), a3);
      }
      a0 += __shfl_xor(a0, 32);
      a1 += __shfl_xor(a1, 32);
      a2 += __shfl_xor(a2, 32);
      a3 += __shfl_xor(a3, 32);
      if (h == 0) {
        a0 *= sc; a1 *= sc; a2 *= sc; a3 *= sc;
        lds_h[r][c * 2]     = pack_bf2(a0, a1);
        lds_h[r][c * 2 + 1] = pack_bf2(a2, a3);
      }
    }
  }
  __syncthreads();

  // ---- step 2: MFMA from LDS ----
  const int q = lane >> 4;
  const int c = lane & 15;
  const int wrowbase = rowbase + wid * 16;

  f32x4_t acc[8];
#pragma unroll
  for (int t = 0; t < 8; ++t) acc[t] = (f32x4_t){0.f, 0.f, 0.f, 0.f};

#pragma unroll
  for (int kk = 0; kk < 4; ++kk) {
    short8_t a = *(const short8_t*)&lds_h[wid * 16 + c][kk * 16 + q * 4];
#pragma unroll
    for (int t = 0; t < 8; ++t) {
      const size_t fo = ((size_t)(t * 4 + kk) * 64 + lane) * 8;
      short8_t bh = *(const short8_t*)(Bhi + fo);
      short8_t bl = *(const short8_t*)(Blo + fo);
      acc[t] = __builtin_amdgcn_mfma_f32_16x16x32_bf16(a, bh, acc[t], 0, 0, 0);
      acc[t] = __builtin_amdgcn_mfma_f32_16x16x32_bf16(a, bl, acc[t], 0, 0, 0);
    }
  }

#pragma unroll
  for (int t = 0; t < 8; ++t) {
    float bias = (t < 4) ? b3[t * 16 + c] : b4[(t - 4) * 16 + c];
    float* obase = (t < 4) ? (outM + t * 16 + c) : (outS + (t - 4) * 16 + c);
#pragma unroll
    for (int rr = 0; rr < 4; ++rr) {
      int row = wrowbase + q * 4 + rr;
      if (row < Nn)
        __builtin_nontemporal_store(acc[t][rr] + bias, obase + (size_t)row * 64);
    }
  }
}

// ---------------- launch ----------------
extern "C" void kernel_launch(void* const* d_in, const int* in_sizes, int n_in,
                              void* d_out, int out_size, void* d_ws, size_t ws_size,
                              hipStream_t stream) {
  const float* x  = (const float*)d_in[0];
  const int*   ei = (const int*)d_in[1];
  const float* W1 = (const float*)d_in[2];
  const float* b1 = (const float*)d_in[3];
  const float* W3 = (const float*)d_in[4];
  const float* b3 = (const float*)d_in[5];
  const float* W4 = (const float*)d_in[6];
  const float* b4 = (const float*)d_in[7];

  const int N = in_sizes[0] / 128;
  const int E = in_sizes[1] / 2;
  const int* src = ei;
  const int* dst = ei + E;
  const bool small = (N <= 65535);
  const size_t esz = small ? sizeof(ushort_t) : sizeof(int);

  // buckets: ranges of (1<<shift) nodes, at most 512 buckets (LDS histogram size)
  int shift = 7;
  while (((N + (1 << shift) - 1) >> shift) > 512) ++shift;
  const int NB = (N + (1 << shift) - 1) >> shift;
  const int C = (E / NB) * 3 / 2 + 512;  // per-bucket capacity, ~1.5x mean + slack

  char* w = (char*)d_ws;
  size_t off = 0;
  auto carve = [&](size_t bytes) { void* p = w + off; off = align256(off + bytes); return p; };
  int*      deg       = (int*)carve((size_t)N * sizeof(int));
  int*      bucketcnt = (int*)carve(512 * sizeof(int));
  uint2*    buckets   = (uint2*)carve((size_t)NB * C * sizeof(uint2));
  void*     edge      = carve((size_t)N * MAXDEG * esz);
  uint_t*   bufG      = (uint_t*)carve((size_t)N * 64 * sizeof(uint_t));  // [N,128] bf16
  uint_t*   bufH      = (uint_t*)carve((size_t)N * 64 * sizeof(uint_t));
  ushort_t* B1hi      = (ushort_t*)carve((size_t)16384 * sizeof(ushort_t));
  ushort_t* B1lo      = (ushort_t*)carve((size_t)16384 * sizeof(ushort_t));
  ushort_t* B2hi      = (ushort_t*)carve((size_t)16384 * sizeof(ushort_t));
  ushort_t* B2lo      = (ushort_t*)carve((size_t)16384 * sizeof(ushort_t));

  float* out_mean = (float*)d_out;
  float* out_std  = out_mean + (size_t)N * 64;

  const int gblocks = (N + 63) / 64;
  const int ablocks = (N + 3) / 4;
  const int sblocks = (E + 2047) / 2048;

  pack_w_kernel<<<16, 256, 0, stream>>>(W1, W3, W4, B1hi, B1lo, B2hi, B2lo, bucketcnt);
  bucket_scatter_kernel<<<sblocks, 256, 0, stream>>>(src, dst, buckets, bucketcnt, E, C, shift, NB);

  if (small) {
    ushort_t* es = (ushort_t*)edge;
    bucket_to_rows_kernel<ushort_t, 128><<<NB, 256, 0, stream>>>(
        buckets, bucketcnt, es, deg, N, C, shift);
    gemm1_mfma_kernel<<<gblocks, 256, 0, stream>>>(x, B1hi, B1lo, (ushort_t*)bufG, N);
    aggregate1_kernel<ushort_t><<<ablocks, 256, 0, stream>>>(bufG, deg, es, b1, bufH, N);
    agg2_gemm2_kernel<ushort_t><<<gblocks, 256, 0, stream>>>(
        bufH, deg, es, B2hi, B2lo, b3, b4, out_mean, out_std, N);
  } else {
    int* es = (int*)edge;
    bucket_to_rows_kernel<int, 128><<<NB, 256, 0, stream>>>(
        buckets, bucketcnt, es, deg, N, C, shift);
    gemm1_mfma_kernel<<<gblocks, 256, 0, stream>>>(x, B1hi, B1lo, (ushort_t*)bufG, N);
    aggregate1_kernel<int><<<ablocks, 256, 0, stream>>>(bufG, deg, es, b1, bufH, N);
    agg2_gemm2_kernel<int><<<gblocks, 256, 0, stream>>>(
        bufH, deg, es, B2hi, B2lo, b3, b4, out_mean, out_std, N);
  }
}

// Round 12
// 128.476 us; speedup vs baseline: 1.0535x; 1.0535x over previous
//
#include <hip/hip_runtime.h>

typedef unsigned int uint_t;
typedef unsigned short ushort_t;

constexpr int MAXDEG = 64;   // slots per node row; deg ~ Poisson(16): P(deg >= 64) ~ 3e-22
// R1: cacheline-padding cursor REGRESSED — same-line atomic contention is NOT the issue.
// R2: batching 4 atomics 114->73us — atomic LATENCY chain was ~40us.
// R3: vmcnt-overlap schedule: NULL — fill cost is memory-side THROUGHPUT.
// R4: XCD-sliced edge regions: NULL — write excess tracks the ATOMIC count (64B/atomic).
// R5: gemm2 -> bf16 MFMA split-W (Whi+Wlo, fp32 acc): WIN 175->167, absmax unchanged.
// R6: pair-gather aggs: ~5us win; "BW-bound" conclusion PARTIALLY WRONG (see R12).
// R7: LDS-binned CSR build at 49 blocks = 1.7% occupancy: 43.8us. Needs parallelism.
// R8: shift=7 (128-node buckets): WIN 177->145.6. Build ~8us total.
// R9: gemm1 MFMA: CRASHED (bucketcnt zeroing bug). R10: fixed: WIN 145.6->126.2.
// R11: fused agg2+gemm2: REGRESSED (57us). Counters exposed the real issue: FETCH=79.5MB
//     for a 12.8MB gather source — agg1's NON-TEMPORAL stores bypass L2/L3, so bufH lived
//     only in HBM and the random gathers were HBM-served at ~2TB/s.
// R12: revert fusion (per pre-commit); agg outputs -> plain CACHED stores so the gather
//     source stays L3-resident. NT kept only for final outputs (never re-read).

// ---------------- bf16 helpers (RNE) ----------------
static __device__ __forceinline__ uint_t f2bf_bits(float f) {
  uint_t u = __builtin_bit_cast(uint_t, f);
  return (u + 0x7fffu + ((u >> 16) & 1u)) >> 16;
}
static __device__ __forceinline__ uint_t pack_bf2(float lo, float hi) {
  return f2bf_bits(lo) | (f2bf_bits(hi) << 16);
}
static __device__ __forceinline__ float bf_lo(uint_t u) {
  return __builtin_bit_cast(float, u << 16);
}
static __device__ __forceinline__ float bf_hi(uint_t u) {
  return __builtin_bit_cast(float, u & 0xffff0000u);
}

// ---------------- vector types ----------------
typedef __attribute__((ext_vector_type(2))) uint_t v2u;
typedef __attribute__((ext_vector_type(8))) short  short8_t;  // 8 bf16 (4 VGPRs)
typedef __attribute__((ext_vector_type(4))) float  f32x4_t;   // MFMA acc

static inline size_t align256(size_t x) { return (x + 255) & ~(size_t)255; }

// ---------------- Phase A: bin edges into dst-range buckets (<=512) ----------------
__global__ __launch_bounds__(256) void bucket_scatter_kernel(
    const int* __restrict__ src, const int* __restrict__ dst,
    uint2* __restrict__ buckets, int* __restrict__ bucketcnt,
    int E, int C, int shift, int NB) {
  __shared__ int hist[512];
  __shared__ int base[512];
  const int tid = threadIdx.x;
  const int e0 = blockIdx.x * 2048;

  for (int i = tid; i < NB; i += 256) hist[i] = 0;
  __syncthreads();

  int dd[8], ss[8], slot[8];
#pragma unroll
  for (int i = 0; i < 8; ++i) {
    int e = e0 + tid + i * 256;
    bool ok = (e < E);
    dd[i] = ok ? dst[e] : -1;
    ss[i] = ok ? src[e] : 0;
    slot[i] = ok ? atomicAdd(&hist[dd[i] >> shift], 1) : 0;
  }
  __syncthreads();

  for (int i = tid; i < NB; i += 256) {
    int c = hist[i];
    base[i] = (c > 0) ? atomicAdd(&bucketcnt[i], c) : 0;
  }
  __syncthreads();

#pragma unroll
  for (int i = 0; i < 8; ++i) {
    if (dd[i] < 0) continue;
    int b = dd[i] >> shift;
    int pos = base[b] + slot[i];
    if (pos >= 0 && pos < C)  // capacity + sign guard
      buckets[(size_t)b * C + pos] = make_uint2((uint_t)dd[i], (uint_t)ss[i]);
  }
}

// ---------------- Phase B: bucket -> 64-slot CSR rows + deg, all in LDS ----------------
template<typename IdxT, int WIN>
__global__ __launch_bounds__(256) void bucket_to_rows_kernel(
    const uint2* __restrict__ buckets, const int* __restrict__ bucketcnt,
    IdxT* __restrict__ edge, int* __restrict__ deg, int Nn, int C, int shift) {
  __shared__ __align__(16) IdxT rows[WIN * MAXDEG];
  __shared__ int cnt[WIN];
  const int tid = threadIdx.x;
  const int b = blockIdx.x;
  const int node0 = b << shift;
  const int RANGE = 1 << shift;
  int ec = bucketcnt[b];
  if (ec > C) ec = C;
  if (ec < 0) ec = 0;
  const uint2* bb = buckets + (size_t)b * C;

  for (int w0 = 0; w0 < RANGE; w0 += WIN) {
    for (int i = tid; i < WIN; i += 256) cnt[i] = 0;
    __syncthreads();
    for (int i = tid; i < ec; i += 256) {
      uint2 it = bb[i];
      int local = (int)it.x - node0 - w0;
      if (local >= 0 && local < WIN) {
        int sl = atomicAdd(&cnt[local], 1);
        if (sl < MAXDEG) rows[local * MAXDEG + sl] = (IdxT)it.y;
      }
    }
    __syncthreads();
    const int nbase = node0 + w0;
    constexpr int PER = (MAXDEG * sizeof(IdxT)) / 16;  // uint4 per node row
    const uint4* rv = (const uint4*)rows;
    uint4* ev = (uint4*)(edge + (size_t)nbase * MAXDEG);
    for (int i = tid; i < WIN * PER; i += 256) {
      int node = nbase + i / PER;
      if (node < Nn) ev[i] = rv[i];
    }
    for (int i = tid; i < WIN; i += 256) {
      int node = nbase + i;
      if (node < Nn) deg[node] = cnt[i];  // raw count (agg clamps)
    }
    __syncthreads();
  }
}

// ---------------- pack weights into MFMA B-fragment order, split hi/lo ----------------
// Blocks 0-7:  W1 (128x128)       -> B1hi/B1lo
// Blocks 8-15: [W3|W4] (128x128)  -> B2hi/B2lo
// Block 0 also zeroes bucketcnt[512] (2 entries/thread).
__global__ __launch_bounds__(256) void pack_w_kernel(
    const float* __restrict__ W1, const float* __restrict__ W3,
    const float* __restrict__ W4,
    ushort_t* __restrict__ B1hi, ushort_t* __restrict__ B1lo,
    ushort_t* __restrict__ B2hi, ushort_t* __restrict__ B2lo,
    int* __restrict__ bucketcnt) {
  if (blockIdx.x == 0) {
    bucketcnt[threadIdx.x] = 0;
    bucketcnt[threadIdx.x + 256] = 0;
  }
  const bool w1 = (blockIdx.x < 8);
  int u = (w1 ? blockIdx.x : blockIdx.x - 8) * 256 + threadIdx.x;  // 0..2047
  int l = u & 63, kk = (u >> 6) & 3, t = u >> 8;
  int q = l >> 4, c = l & 15;
  int n = t * 16 + c;
  short8_t vh, vl;
#pragma unroll
  for (int j = 0; j < 8; ++j) {
    int k = kk * 32 + q * 8 + j;
    float w;
    if (w1)          w = W1[(size_t)k * 128 + n];
    else if (n < 64) w = W3[(size_t)k * 64 + n];
    else             w = W4[(size_t)k * 64 + (n - 64)];
    uint_t hb = f2bf_bits(w);
    float wl = w - __builtin_bit_cast(float, hb << 16);
    vh[j] = (short)hb;
    vl[j] = (short)f2bf_bits(wl);
  }
  ushort_t* ph = w1 ? B1hi : B2hi;
  ushort_t* pl = w1 ? B1lo : B2lo;
  *(short8_t*)(ph + (size_t)u * 8) = vh;
  *(short8_t*)(pl + (size_t)u * 8) = vl;
}

// ---------------- GEMM1 (MFMA): outG(bf16) = X @ W1, both operands hi/lo-split ----------------
__global__ __launch_bounds__(256) void gemm1_mfma_kernel(
    const float* __restrict__ X, const ushort_t* __restrict__ Bhi,
    const ushort_t* __restrict__ Blo, ushort_t* __restrict__ outG, int Nrows) {
  const int tid = threadIdx.x;
  const int wid = tid >> 6;
  const int lane = tid & 63;
  const int q = lane >> 4;
  const int c = lane & 15;
  const int rowbase = blockIdx.x * 64 + wid * 16;

  f32x4_t acc[8];
#pragma unroll
  for (int t = 0; t < 8; ++t) acc[t] = (f32x4_t){0.f, 0.f, 0.f, 0.f};

  int arow = rowbase + c;
  int ars = (arow < Nrows) ? arow : (Nrows - 1);
  const float* abase = X + (size_t)ars * 128 + q * 8;

#pragma unroll
  for (int kk = 0; kk < 4; ++kk) {
    float4 xa = *(const float4*)(abase + kk * 32);
    float4 xb = *(const float4*)(abase + kk * 32 + 4);
    float xf[8] = {xa.x, xa.y, xa.z, xa.w, xb.x, xb.y, xb.z, xb.w};
    short8_t ahi, alo;
#pragma unroll
    for (int j = 0; j < 8; ++j) {
      float f = xf[j];
      uint_t hb = f2bf_bits(f);
      ahi[j] = (short)hb;
      float fl = f - __builtin_bit_cast(float, hb << 16);
      alo[j] = (short)f2bf_bits(fl);
    }
#pragma unroll
    for (int t = 0; t < 8; ++t) {
      const size_t fo = ((size_t)(t * 4 + kk) * 64 + lane) * 8;
      short8_t bh = *(const short8_t*)(Bhi + fo);
      short8_t bl = *(const short8_t*)(Blo + fo);
      acc[t] = __builtin_amdgcn_mfma_f32_16x16x32_bf16(ahi, bh, acc[t], 0, 0, 0);
      acc[t] = __builtin_amdgcn_mfma_f32_16x16x32_bf16(ahi, bl, acc[t], 0, 0, 0);
      acc[t] = __builtin_amdgcn_mfma_f32_16x16x32_bf16(alo, bh, acc[t], 0, 0, 0);
    }
  }

  // plain cached stores: outG is the next kernel's random-gather source — keep it L3-resident
#pragma unroll
  for (int t = 0; t < 8; ++t) {
#pragma unroll
    for (int rr = 0; rr < 4; ++rr) {
      int row = rowbase + q * 4 + rr;
      if (row < Nrows)
        outG[(size_t)row * 128 + t * 16 + c] = (ushort_t)f2bf_bits(acc[t][rr]);
    }
  }
}

// ---------------- GEMM2 (MFMA): mean/std(fp32) = Xbf @ (Whi + Wlo) + [b3|b4] ----------------
__global__ __launch_bounds__(256) void gemm2_mfma_kernel(
    const ushort_t* __restrict__ Xbf, const ushort_t* __restrict__ Bhi,
    const ushort_t* __restrict__ Blo, const float* __restrict__ b3,
    const float* __restrict__ b4, float* __restrict__ outM,
    float* __restrict__ outS, int Nrows) {
  const int tid = threadIdx.x;
  const int wid = tid >> 6;
  const int lane = tid & 63;
  const int q = lane >> 4;
  const int c = lane & 15;
  const int rowbase = blockIdx.x * 64 + wid * 16;

  f32x4_t acc[8];
#pragma unroll
  for (int t = 0; t < 8; ++t) acc[t] = (f32x4_t){0.f, 0.f, 0.f, 0.f};

  int arow = rowbase + c;
  int ars = (arow < Nrows) ? arow : (Nrows - 1);
  const ushort_t* abase = Xbf + (size_t)ars * 128 + q * 8;

#pragma unroll
  for (int kk = 0; kk < 4; ++kk) {
    short8_t a = *(const short8_t*)(abase + kk * 32);
#pragma unroll
    for (int t = 0; t < 8; ++t) {
      const size_t fo = ((size_t)(t * 4 + kk) * 64 + lane) * 8;
      short8_t bh = *(const short8_t*)(Bhi + fo);
      short8_t bl = *(const short8_t*)(Blo + fo);
      acc[t] = __builtin_amdgcn_mfma_f32_16x16x32_bf16(a, bh, acc[t], 0, 0, 0);
      acc[t] = __builtin_amdgcn_mfma_f32_16x16x32_bf16(a, bl, acc[t], 0, 0, 0);
    }
  }

  // final outputs: NT is fine here (never re-read)
#pragma unroll
  for (int t = 0; t < 8; ++t) {
    float bias = (t < 4) ? b3[t * 16 + c] : b4[(t - 4) * 16 + c];
    float* obase = (t < 4) ? (outM + t * 16 + c) : (outS + (t - 4) * 16 + c);
#pragma unroll
    for (int rr = 0; rr < 4; ++rr) {
      int row = rowbase + q * 4 + rr;
      if (row < Nrows)
        __builtin_nontemporal_store(acc[t][rr] + bias, obase + (size_t)row * 64);
    }
  }
}

// ---------------- gather aggregation: pair-gather (bf16 in/out, fp32 accum) ----------------
// Output store is CACHED (not NT): the result buffer is the next kernel's gather source.
template<int EPI, bool SRCDV, typename IdxT>
__global__ __launch_bounds__(256) void aggregate_kernel(
    const uint_t* __restrict__ g, const int* __restrict__ deg,
    const IdxT* __restrict__ edge, const float* __restrict__ b1,
    uint_t* __restrict__ out, int Nn) {
  const int wave = threadIdx.x >> 6;
  const int lane = threadIdx.x & 63;
  const int n = blockIdx.x * 4 + wave;
  if (n >= Nn) return;
  const int dn = deg[n];
  const int cnt = (dn > 63) ? 63 : dn;
  const float sc = rsqrtf((float)(dn + 1));

  int vl = n;
  if (lane >= 1 && lane <= cnt) vl = (int)edge[(size_t)n * MAXDEG + (lane - 1)];
  float wl = 0.f;
  if (lane == 0)        wl = SRCDV ? sc : 1.f;
  else if (lane <= cnt) wl = SRCDV ? rsqrtf((float)(deg[vl] + 1)) : 1.f;

  const int h = lane >> 5;
  const int c = lane & 31;
  const uint_t* gc = g + c * 2;

  float a0 = 0.f, a1 = 0.f, a2 = 0.f, a3 = 0.f;
  const int entries = cnt + 1;
  const int npairs = (entries + 1) >> 1;

  int p = 0;
  for (; p + 4 <= npairs; p += 4) {
    int ss[4]; float ww[4]; uint2 uu[4];
#pragma unroll
    for (int t = 0; t < 4; ++t) {
      int j = 2 * (p + t) + h;
      ss[t] = __shfl(vl, j);
      ww[t] = __shfl(wl, j);
    }
#pragma unroll
    for (int t = 0; t < 4; ++t)
      uu[t] = *(const uint2*)(gc + (size_t)ss[t] * 64);
#pragma unroll
    for (int t = 0; t < 4; ++t) {
      a0 = fmaf(ww[t], bf_lo(uu[t].x), a0);
      a1 = fmaf(ww[t], bf_hi(uu[t].x), a1);
      a2 = fmaf(ww[t], bf_lo(uu[t].y), a2);
      a3 = fmaf(ww[t], bf_hi(uu[t].y), a3);
    }
  }
  for (; p < npairs; ++p) {
    int j = 2 * p + h;
    int s0 = __shfl(vl, j);
    float w0 = __shfl(wl, j);
    uint2 u = *(const uint2*)(gc + (size_t)s0 * 64);
    a0 = fmaf(w0, bf_lo(u.x), a0);
    a1 = fmaf(w0, bf_hi(u.x), a1);
    a2 = fmaf(w0, bf_lo(u.y), a2);
    a3 = fmaf(w0, bf_hi(u.y), a3);
  }

  a0 += __shfl_xor(a0, 32);
  a1 += __shfl_xor(a1, 32);
  a2 += __shfl_xor(a2, 32);
  a3 += __shfl_xor(a3, 32);

  if (h == 0) {
    if (EPI == 1) {
      float4 b = ((const float4*)b1)[c];
      a0 = fmaxf(fmaf(sc, a0, b.x), 0.f) * sc;
      a1 = fmaxf(fmaf(sc, a1, b.y), 0.f) * sc;
      a2 = fmaxf(fmaf(sc, a2, b.z), 0.f) * sc;
      a3 = fmaxf(fmaf(sc, a3, b.w), 0.f) * sc;
    } else {
      a0 *= sc; a1 *= sc; a2 *= sc; a3 *= sc;
    }
    *(uint2*)(out + (size_t)n * 64 + c * 2) =
        make_uint2(pack_bf2(a0, a1), pack_bf2(a2, a3));  // cached, NOT non-temporal
  }
}

// ---------------- launch ----------------
extern "C" void kernel_launch(void* const* d_in, const int* in_sizes, int n_in,
                              void* d_out, int out_size, void* d_ws, size_t ws_size,
                              hipStream_t stream) {
  const float* x  = (const float*)d_in[0];
  const int*   ei = (const int*)d_in[1];
  const float* W1 = (const float*)d_in[2];
  const float* b1 = (const float*)d_in[3];
  const float* W3 = (const float*)d_in[4];
  const float* b3 = (const float*)d_in[5];
  const float* W4 = (const float*)d_in[6];
  const float* b4 = (const float*)d_in[7];

  const int N = in_sizes[0] / 128;
  const int E = in_sizes[1] / 2;
  const int* src = ei;
  const int* dst = ei + E;
  const bool small = (N <= 65535);
  const size_t esz = small ? sizeof(ushort_t) : sizeof(int);

  // buckets: ranges of (1<<shift) nodes, at most 512 buckets (LDS histogram size)
  int shift = 7;
  while (((N + (1 << shift) - 1) >> shift) > 512) ++shift;
  const int NB = (N + (1 << shift) - 1) >> shift;
  const int C = (E / NB) * 3 / 2 + 512;  // per-bucket capacity, ~1.5x mean + slack

  char* w = (char*)d_ws;
  size_t off = 0;
  auto carve = [&](size_t bytes) { void* p = w + off; off = align256(off + bytes); return p; };
  int*      deg       = (int*)carve((size_t)N * sizeof(int));
  int*      bucketcnt = (int*)carve(512 * sizeof(int));
  uint2*    buckets   = (uint2*)carve((size_t)NB * C * sizeof(uint2));
  void*     edge      = carve((size_t)N * MAXDEG * esz);
  uint_t*   bufG      = (uint_t*)carve((size_t)N * 64 * sizeof(uint_t));  // [N,128] bf16
  uint_t*   bufH      = (uint_t*)carve((size_t)N * 64 * sizeof(uint_t));
  ushort_t* B1hi      = (ushort_t*)carve((size_t)16384 * sizeof(ushort_t));
  ushort_t* B1lo      = (ushort_t*)carve((size_t)16384 * sizeof(ushort_t));
  ushort_t* B2hi      = (ushort_t*)carve((size_t)16384 * sizeof(ushort_t));
  ushort_t* B2lo      = (ushort_t*)carve((size_t)16384 * sizeof(ushort_t));

  float* out_mean = (float*)d_out;
  float* out_std  = out_mean + (size_t)N * 64;

  const int gblocks = (N + 63) / 64;
  const int ablocks = (N + 3) / 4;
  const int sblocks = (E + 2047) / 2048;

  pack_w_kernel<<<16, 256, 0, stream>>>(W1, W3, W4, B1hi, B1lo, B2hi, B2lo, bucketcnt);
  bucket_scatter_kernel<<<sblocks, 256, 0, stream>>>(src, dst, buckets, bucketcnt, E, C, shift, NB);

  if (small) {
    ushort_t* es = (ushort_t*)edge;
    bucket_to_rows_kernel<ushort_t, 128><<<NB, 256, 0, stream>>>(
        buckets, bucketcnt, es, deg, N, C, shift);
    gemm1_mfma_kernel<<<gblocks, 256, 0, stream>>>(x, B1hi, B1lo, (ushort_t*)bufG, N);
    aggregate_kernel<1, true,  ushort_t><<<ablocks, 256, 0, stream>>>(bufG, deg, es, b1, bufH, N);
    aggregate_kernel<2, false, ushort_t><<<ablocks, 256, 0, stream>>>(bufH, deg, es, nullptr, bufG, N);
  } else {
    int* es = (int*)edge;
    bucket_to_rows_kernel<int, 128><<<NB, 256, 0, stream>>>(
        buckets, bucketcnt, es, deg, N, C, shift);
    gemm1_mfma_kernel<<<gblocks, 256, 0, stream>>>(x, B1hi, B1lo, (ushort_t*)bufG, N);
    aggregate_kernel<1, true,  int><<<ablocks, 256, 0, stream>>>(bufG, deg, es, b1, bufH, N);
    aggregate_kernel<2, false, int><<<ablocks, 256, 0, stream>>>(bufH, deg, es, nullptr, bufG, N);
  }
  gemm2_mfma_kernel<<<gblocks, 256, 0, stream>>>(
      (const ushort_t*)bufG, B2hi, B2lo, b3, b4, out_mean, out_std, N);
}